// Round 1
// baseline (1062.353 us; speedup 1.0000x reference)
//
#include <hip/hip_runtime.h>
#include <hip/hip_bf16.h>

// GCN: 5 x (GEMM 64x64 -> CSR gather + bias/ReLU/BN/residual) -> mean-pool -> MLP head.
// CSR-by-dst built on-device each launch (same work every call; graph-capture safe).

#define NNODES 100000
#define NEDGES 1000000
#define NGRAPH 64
#define HDIM 64

// ---------------- zero ----------------
__global__ void zero_kernel(int* __restrict__ p, int n) {
    int i = blockIdx.x * 256 + threadIdx.x;
    if (i < n) p[i] = 0;
}

// ---------------- degree count (in-degree via dst) ----------------
__global__ void count_kernel(const int* __restrict__ ei, int* __restrict__ counts, int E) {
    int e = blockIdx.x * 256 + threadIdx.x;
    if (e < E) atomicAdd(&counts[ei[E + e]], 1);
}

// ---------------- single-block exclusive scan of counts -> row_ptr ----------------
__global__ __launch_bounds__(1024) void scan_kernel(const int* __restrict__ counts,
                                                    int* __restrict__ row_ptr, int N) {
    __shared__ int sums[1024];
    int t = threadIdx.x;
    int chunk = (N + 1023) / 1024;
    int start = t * chunk;
    int end = start + chunk; if (end > N) end = N;
    int s = 0;
    for (int i = start; i < end; ++i) s += counts[i];
    sums[t] = s;
    __syncthreads();
    // Hillis-Steele inclusive scan
    for (int off = 1; off < 1024; off <<= 1) {
        int v = (t >= off) ? sums[t - off] : 0;
        __syncthreads();
        sums[t] += v;
        __syncthreads();
    }
    int run = (t == 0) ? 0 : sums[t - 1];   // exclusive prefix
    for (int i = start; i < end; ++i) {
        row_ptr[i] = run;
        run += counts[i];
    }
    if (t == 1023) row_ptr[N] = sums[1023]; // total = E
}

// ---------------- dinv = rsqrt(deg), cursor = row_ptr copy ----------------
__global__ void dinv_kernel(const int* __restrict__ counts, const int* __restrict__ row_ptr,
                            float* __restrict__ dinv, int* __restrict__ cursor, int N) {
    int i = blockIdx.x * 256 + threadIdx.x;
    if (i < N) {
        dinv[i] = rsqrtf((float)(counts[i] + 1));   // +1 for self-loop
        cursor[i] = row_ptr[i];
    }
}

// ---------------- fill CSR buckets ----------------
__global__ void fill_kernel(const int* __restrict__ ei, const float* __restrict__ dinv,
                            int* __restrict__ cursor, int* __restrict__ csr_src,
                            float* __restrict__ csr_norm, int E) {
    int e = blockIdx.x * 256 + threadIdx.x;
    if (e < E) {
        int s = ei[e];
        int d = ei[E + e];
        int p = atomicAdd(&cursor[d], 1);
        csr_src[p] = s;
        csr_norm[p] = dinv[s] * dinv[d];
    }
}

// ---------------- GEMM: T = A(Nx64) @ W(64x64) ----------------
__global__ __launch_bounds__(256) void gemm64_kernel(const float* __restrict__ A,
                                                     const float* __restrict__ W,
                                                     float* __restrict__ T, int N) {
    int row = blockIdx.x * 256 + threadIdx.x;
    if (row >= N) return;
    const float4* arow = (const float4*)(A + (size_t)row * HDIM);
    float acc[HDIM];
#pragma unroll
    for (int j = 0; j < HDIM; ++j) acc[j] = 0.f;
    for (int kk = 0; kk < 16; ++kk) {
        float4 a4 = arow[kk];
        const float* wr = W + kk * 4 * HDIM;
#pragma unroll
        for (int j = 0; j < HDIM; ++j) acc[j] += a4.x * wr[j];
#pragma unroll
        for (int j = 0; j < HDIM; ++j) acc[j] += a4.y * wr[HDIM + j];
#pragma unroll
        for (int j = 0; j < HDIM; ++j) acc[j] += a4.z * wr[2 * HDIM + j];
#pragma unroll
        for (int j = 0; j < HDIM; ++j) acc[j] += a4.w * wr[3 * HDIM + j];
    }
    float4* orow = (float4*)(T + (size_t)row * HDIM);
#pragma unroll
    for (int j = 0; j < 16; ++j)
        orow[j] = make_float4(acc[4 * j], acc[4 * j + 1], acc[4 * j + 2], acc[4 * j + 3]);
}

// ---------------- gather + bias + ReLU + BN + residual (one wave per node) -------------
__global__ __launch_bounds__(256) void aggregate_kernel(
    const float* __restrict__ T, const float* __restrict__ dinv,
    const int* __restrict__ row_ptr, const int* __restrict__ csr_src,
    const float* __restrict__ csr_norm,
    const float* __restrict__ bias, const float* __restrict__ gamma,
    const float* __restrict__ beta, const float* __restrict__ mean,
    const float* __restrict__ var,
    float* __restrict__ P, int N, int residual) {
    int node = (blockIdx.x * 256 + threadIdx.x) >> 6;
    int lane = threadIdx.x & 63;
    if (node >= N) return;
    float di = dinv[node];
    float acc = T[(size_t)node * HDIM + lane] * di * di;  // self-loop
    int e0 = row_ptr[node], e1 = row_ptr[node + 1];
    for (int e = e0; e < e1; ++e) {
        int s = csr_src[e];
        float nrm = csr_norm[e];
        acc += T[(size_t)s * HDIM + lane] * nrm;
    }
    float v = acc + bias[lane];
    v = fmaxf(v, 0.f);
    v = (v - mean[lane]) * rsqrtf(var[lane] + 1e-5f) * gamma[lane] + beta[lane];
    if (residual) v += P[(size_t)node * HDIM + lane];
    P[(size_t)node * HDIM + lane] = v;
}

// ---------------- mean-pool: per-wave run accumulation over sorted batch ---------------
__global__ __launch_bounds__(256) void pool_kernel(const float* __restrict__ P,
                                                   const int* __restrict__ batch,
                                                   float* __restrict__ gsum,
                                                   float* __restrict__ gcnt, int N) {
    int wave = (blockIdx.x * 256 + threadIdx.x) >> 6;
    int lane = threadIdx.x & 63;
    int start = wave * 64;
    if (start >= N) return;
    int end = start + 64; if (end > N) end = N;
    float acc = 0.f;
    int cur = batch[start];
    int cnt = 0;
    for (int i = start; i < end; ++i) {
        int b = batch[i];
        if (b != cur) {
            atomicAdd(&gsum[cur * HDIM + lane], acc);
            if (lane == 0) atomicAdd(&gcnt[cur], (float)cnt);
            cur = b; acc = 0.f; cnt = 0;
        }
        acc += P[(size_t)i * HDIM + lane];
        cnt++;
    }
    atomicAdd(&gsum[cur * HDIM + lane], acc);
    if (lane == 0) atomicAdd(&gcnt[cur], (float)cnt);
}

// ---------------- MLP head (single block) ----------------
__global__ __launch_bounds__(256) void head_kernel(
    const float* __restrict__ gsum, const float* __restrict__ gcnt,
    const float* __restrict__ hW1, const float* __restrict__ hb1,
    const float* __restrict__ hgam, const float* __restrict__ hbet,
    const float* __restrict__ hm, const float* __restrict__ hv,
    const float* __restrict__ hW2, const float* __restrict__ hb2,
    float* __restrict__ out) {
    __shared__ float g[NGRAPH * HDIM];
    __shared__ float h1[NGRAPH * 32];
    int t = threadIdx.x;
    for (int idx = t; idx < NGRAPH * HDIM; idx += 256) {
        int gi = idx >> 6;
        g[idx] = gsum[idx] / fmaxf(gcnt[gi], 1.f);
    }
    __syncthreads();
    for (int idx = t; idx < NGRAPH * 32; idx += 256) {
        int gi = idx >> 5, j = idx & 31;
        float s = hb1[j];
#pragma unroll
        for (int f = 0; f < HDIM; ++f) s += g[gi * HDIM + f] * hW1[f * 32 + j];
        s = fmaxf(s, 0.f);
        s = (s - hm[j]) * rsqrtf(hv[j] + 1e-5f) * hgam[j] + hbet[j];
        h1[idx] = s;
    }
    __syncthreads();
    if (t < NGRAPH) {
        float s = hb2[0];
#pragma unroll
        for (int j = 0; j < 32; ++j) s += h1[t * 32 + j] * hW2[j];
        out[t] = s;
    }
}

static inline size_t align_up(size_t x) { return (x + 255) & ~(size_t)255; }

extern "C" void kernel_launch(void* const* d_in, const int* in_sizes, int n_in,
                              void* d_out, int out_size, void* d_ws, size_t ws_size,
                              hipStream_t stream) {
    const float* x    = (const float*)d_in[0];
    const int*   ei   = (const int*)d_in[1];
    const int*   batch= (const int*)d_in[2];
    const float* Wc   = (const float*)d_in[3];
    const float* bc   = (const float*)d_in[4];
    const float* bng  = (const float*)d_in[5];
    const float* bnb  = (const float*)d_in[6];
    const float* bnm  = (const float*)d_in[7];
    const float* bnv  = (const float*)d_in[8];
    const float* hW1  = (const float*)d_in[9];
    const float* hb1  = (const float*)d_in[10];
    const float* hgam = (const float*)d_in[11];
    const float* hbet = (const float*)d_in[12];
    const float* hm   = (const float*)d_in[13];
    const float* hv   = (const float*)d_in[14];
    const float* hW2  = (const float*)d_in[15];
    const float* hb2  = (const float*)d_in[16];
    float* out = (float*)d_out;

    const int N = in_sizes[0] / HDIM;   // 100000
    const int E = in_sizes[1] / 2;      // 1000000

    // ---- workspace carve (all 256B aligned) ----
    char* ws = (char*)d_ws;
    size_t off = 0;
    float* P = (float*)(ws + off);        off += align_up((size_t)N * HDIM * 4);
    float* T = (float*)(ws + off);        off += align_up((size_t)N * HDIM * 4);
    // contiguous zero region: counts | gsum | gcnt
    int*   counts = (int*)(ws + off);
    float* gsum = (float*)(ws + off + (size_t)N * 4);
    float* gcnt = (float*)(ws + off + (size_t)N * 4 + NGRAPH * HDIM * 4);
    int zero_n = N + NGRAPH * HDIM + NGRAPH;
    off += align_up((size_t)zero_n * 4);
    int*   row_ptr = (int*)(ws + off);    off += align_up((size_t)(N + 1) * 4);
    int*   cursor  = (int*)(ws + off);    off += align_up((size_t)N * 4);
    float* dinv    = (float*)(ws + off);  off += align_up((size_t)N * 4);
    int*   csr_src = (int*)(ws + off);    off += align_up((size_t)E * 4);
    float* csr_norm= (float*)(ws + off);  off += align_up((size_t)E * 4);

    int gE = (E + 255) / 256;
    int gN = (N + 255) / 256;

    // ---- build degree + CSR ----
    zero_kernel<<<(zero_n + 255) / 256, 256, 0, stream>>>(counts, zero_n);
    count_kernel<<<gE, 256, 0, stream>>>(ei, counts, E);
    scan_kernel<<<1, 1024, 0, stream>>>(counts, row_ptr, N);
    dinv_kernel<<<gN, 256, 0, stream>>>(counts, row_ptr, dinv, cursor, N);
    fill_kernel<<<gE, 256, 0, stream>>>(ei, dinv, cursor, csr_src, csr_norm, E);

    // ---- 5 GCN layers ----
    int aggBlocks = (N + 3) / 4;   // 4 waves (nodes) per 256-thread block
    for (int l = 0; l < 5; ++l) {
        const float* in = (l == 0) ? x : P;
        gemm64_kernel<<<gN, 256, 0, stream>>>(in, Wc + (size_t)l * HDIM * HDIM, T, N);
        aggregate_kernel<<<aggBlocks, 256, 0, stream>>>(
            T, dinv, row_ptr, csr_src, csr_norm,
            bc + l * HDIM, bng + l * HDIM, bnb + l * HDIM, bnm + l * HDIM, bnv + l * HDIM,
            P, N, (l > 0) ? 1 : 0);
    }

    // ---- pool + head ----
    int poolBlocks = (N + 255) / 256;  // each block covers 4 waves x 64 nodes
    pool_kernel<<<poolBlocks, 256, 0, stream>>>(P, batch, gsum, gcnt, N);
    head_kernel<<<1, 256, 0, stream>>>(gsum, gcnt, hW1, hb1, hgam, hbet, hm, hv, hW2, hb2, out);
}

// Round 2
// 907.690 us; speedup vs baseline: 1.1704x; 1.1704x over previous
//
#include <hip/hip_runtime.h>
#include <hip/hip_bf16.h>

// GCN: 5 x (GEMM 64x64 -> CSR gather + bias/ReLU/BN/residual) -> mean-pool -> MLP head.
// CSR-by-dst built on-device each launch (same work every call; graph-capture safe).
// R2: hierarchical scan (3 kernels, ~6us) replaces 163us single-block scan; dinv fused in.

#define NNODES 100000
#define NEDGES 1000000
#define NGRAPH 64
#define HDIM 64
#define SCAN_CHUNK 1024   // elements per block in the hierarchical scan

// ---------------- zero ----------------
__global__ void zero_kernel(int* __restrict__ p, int n) {
    int i = blockIdx.x * 256 + threadIdx.x;
    if (i < n) p[i] = 0;
}

// ---------------- degree count (in-degree via dst) ----------------
__global__ void count_kernel(const int* __restrict__ ei, int* __restrict__ counts, int E) {
    int e = blockIdx.x * 256 + threadIdx.x;
    if (e < E) atomicAdd(&counts[ei[E + e]], 1);
}

// ---------------- scan level 1: per-block partial sums (1024 elems / block) -----------
__global__ __launch_bounds__(256) void bsum_kernel(const int* __restrict__ counts,
                                                   int* __restrict__ bsums, int N) {
    __shared__ int ws[4];
    int base = blockIdx.x * SCAN_CHUNK + threadIdx.x * 4;
    int s = 0;
    if (base + 3 < N) {
        int4 c = *(const int4*)(counts + base);
        s = c.x + c.y + c.z + c.w;
    } else {
        for (int k = 0; k < 4 && base + k < N; ++k) s += counts[base + k];
    }
    // wave reduce
    for (int off = 32; off > 0; off >>= 1) s += __shfl_down(s, off, 64);
    int wid = threadIdx.x >> 6;
    if ((threadIdx.x & 63) == 0) ws[wid] = s;
    __syncthreads();
    if (threadIdx.x == 0) bsums[blockIdx.x] = ws[0] + ws[1] + ws[2] + ws[3];
}

// ---------------- scan level 2: single small block scans the partial sums --------------
__global__ __launch_bounds__(256) void bscan_kernel(int* __restrict__ bsums, int nb,
                                                    int* __restrict__ row_ptr, int N, int E) {
    __shared__ int sh[256];
    int t = threadIdx.x;
    sh[t] = (t < nb) ? bsums[t] : 0;
    __syncthreads();
    for (int off = 1; off < 256; off <<= 1) {
        int v = (t >= off) ? sh[t - off] : 0;
        __syncthreads();
        sh[t] += v;
        __syncthreads();
    }
    if (t < nb) bsums[t] = (t == 0) ? 0 : sh[t - 1];  // exclusive block offsets
    if (t == 0) row_ptr[N] = E;                        // total in-degree == E
}

// ---------------- scan level 3: apply — row_ptr + dinv + cursor fused ------------------
__global__ __launch_bounds__(256) void scan_apply_kernel(
    const int* __restrict__ counts, const int* __restrict__ bsums,
    int* __restrict__ row_ptr, int* __restrict__ cursor,
    float* __restrict__ dinv, int N) {
    __shared__ int wsum[4];
    int t = threadIdx.x;
    int lane = t & 63, wid = t >> 6;
    int base = blockIdx.x * SCAN_CHUNK + t * 4;
    int c0 = 0, c1 = 0, c2 = 0, c3 = 0;
    if (base + 3 < N) {
        int4 c = *(const int4*)(counts + base);
        c0 = c.x; c1 = c.y; c2 = c.z; c3 = c.w;
    } else if (base < N) {
        c0 = counts[base];
        if (base + 1 < N) c1 = counts[base + 1];
        if (base + 2 < N) c2 = counts[base + 2];
    }
    int tsum = c0 + c1 + c2 + c3;
    // wave inclusive scan of tsum
    int incl = tsum;
    for (int off = 1; off < 64; off <<= 1) {
        int v = __shfl_up(incl, off, 64);
        if (lane >= off) incl += v;
    }
    if (lane == 63) wsum[wid] = incl;
    __syncthreads();
    int woff = 0;
    for (int w = 0; w < wid; ++w) woff += wsum[w];
    int off0 = bsums[blockIdx.x] + woff + (incl - tsum);  // exclusive offset of element base
    if (base + 3 < N) {
        int4 rp; rp.x = off0; rp.y = off0 + c0; rp.z = off0 + c0 + c1; rp.w = off0 + c0 + c1 + c2;
        *(int4*)(row_ptr + base) = rp;
        *(int4*)(cursor + base) = rp;
        float4 dv;
        dv.x = rsqrtf((float)(c0 + 1)); dv.y = rsqrtf((float)(c1 + 1));
        dv.z = rsqrtf((float)(c2 + 1)); dv.w = rsqrtf((float)(c3 + 1));
        *(float4*)(dinv + base) = dv;
    } else if (base < N) {
        int run = off0;
        int cs[4] = {c0, c1, c2, c3};
        for (int k = 0; k < 4 && base + k < N; ++k) {
            row_ptr[base + k] = run;
            cursor[base + k] = run;
            dinv[base + k] = rsqrtf((float)(cs[k] + 1));
            run += cs[k];
        }
    }
}

// ---------------- fill CSR buckets ----------------
__global__ void fill_kernel(const int* __restrict__ ei, const float* __restrict__ dinv,
                            int* __restrict__ cursor, int* __restrict__ csr_src,
                            float* __restrict__ csr_norm, int E) {
    int e = blockIdx.x * 256 + threadIdx.x;
    if (e < E) {
        int s = ei[e];
        int d = ei[E + e];
        int p = atomicAdd(&cursor[d], 1);
        csr_src[p] = s;
        csr_norm[p] = dinv[s] * dinv[d];
    }
}

// ---------------- GEMM: T = A(Nx64) @ W(64x64) ----------------
__global__ __launch_bounds__(256) void gemm64_kernel(const float* __restrict__ A,
                                                     const float* __restrict__ W,
                                                     float* __restrict__ T, int N) {
    int row = blockIdx.x * 256 + threadIdx.x;
    if (row >= N) return;
    const float4* arow = (const float4*)(A + (size_t)row * HDIM);
    float acc[HDIM];
#pragma unroll
    for (int j = 0; j < HDIM; ++j) acc[j] = 0.f;
    for (int kk = 0; kk < 16; ++kk) {
        float4 a4 = arow[kk];
        const float* wr = W + kk * 4 * HDIM;
#pragma unroll
        for (int j = 0; j < HDIM; ++j) acc[j] += a4.x * wr[j];
#pragma unroll
        for (int j = 0; j < HDIM; ++j) acc[j] += a4.y * wr[HDIM + j];
#pragma unroll
        for (int j = 0; j < HDIM; ++j) acc[j] += a4.z * wr[2 * HDIM + j];
#pragma unroll
        for (int j = 0; j < HDIM; ++j) acc[j] += a4.w * wr[3 * HDIM + j];
    }
    float4* orow = (float4*)(T + (size_t)row * HDIM);
#pragma unroll
    for (int j = 0; j < 16; ++j)
        orow[j] = make_float4(acc[4 * j], acc[4 * j + 1], acc[4 * j + 2], acc[4 * j + 3]);
}

// ---------------- gather + bias + ReLU + BN + residual (one wave per node) -------------
__global__ __launch_bounds__(256) void aggregate_kernel(
    const float* __restrict__ T, const float* __restrict__ dinv,
    const int* __restrict__ row_ptr, const int* __restrict__ csr_src,
    const float* __restrict__ csr_norm,
    const float* __restrict__ bias, const float* __restrict__ gamma,
    const float* __restrict__ beta, const float* __restrict__ mean,
    const float* __restrict__ var,
    float* __restrict__ P, int N, int residual) {
    int node = (blockIdx.x * 256 + threadIdx.x) >> 6;
    int lane = threadIdx.x & 63;
    if (node >= N) return;
    float di = dinv[node];
    float acc = T[(size_t)node * HDIM + lane] * di * di;  // self-loop
    int e0 = row_ptr[node], e1 = row_ptr[node + 1];
    for (int e = e0; e < e1; ++e) {
        int s = csr_src[e];
        float nrm = csr_norm[e];
        acc += T[(size_t)s * HDIM + lane] * nrm;
    }
    float v = acc + bias[lane];
    v = fmaxf(v, 0.f);
    v = (v - mean[lane]) * rsqrtf(var[lane] + 1e-5f) * gamma[lane] + beta[lane];
    if (residual) v += P[(size_t)node * HDIM + lane];
    P[(size_t)node * HDIM + lane] = v;
}

// ---------------- mean-pool: per-wave run accumulation over sorted batch ---------------
__global__ __launch_bounds__(256) void pool_kernel(const float* __restrict__ P,
                                                   const int* __restrict__ batch,
                                                   float* __restrict__ gsum,
                                                   float* __restrict__ gcnt, int N) {
    int wave = (blockIdx.x * 256 + threadIdx.x) >> 6;
    int lane = threadIdx.x & 63;
    int start = wave * 64;
    if (start >= N) return;
    int end = start + 64; if (end > N) end = N;
    float acc = 0.f;
    int cur = batch[start];
    int cnt = 0;
    for (int i = start; i < end; ++i) {
        int b = batch[i];
        if (b != cur) {
            atomicAdd(&gsum[cur * HDIM + lane], acc);
            if (lane == 0) atomicAdd(&gcnt[cur], (float)cnt);
            cur = b; acc = 0.f; cnt = 0;
        }
        acc += P[(size_t)i * HDIM + lane];
        cnt++;
    }
    atomicAdd(&gsum[cur * HDIM + lane], acc);
    if (lane == 0) atomicAdd(&gcnt[cur], (float)cnt);
}

// ---------------- MLP head (single block) ----------------
__global__ __launch_bounds__(256) void head_kernel(
    const float* __restrict__ gsum, const float* __restrict__ gcnt,
    const float* __restrict__ hW1, const float* __restrict__ hb1,
    const float* __restrict__ hgam, const float* __restrict__ hbet,
    const float* __restrict__ hm, const float* __restrict__ hv,
    const float* __restrict__ hW2, const float* __restrict__ hb2,
    float* __restrict__ out) {
    __shared__ float g[NGRAPH * HDIM];
    __shared__ float h1[NGRAPH * 32];
    int t = threadIdx.x;
    for (int idx = t; idx < NGRAPH * HDIM; idx += 256) {
        int gi = idx >> 6;
        g[idx] = gsum[idx] / fmaxf(gcnt[gi], 1.f);
    }
    __syncthreads();
    for (int idx = t; idx < NGRAPH * 32; idx += 256) {
        int gi = idx >> 5, j = idx & 31;
        float s = hb1[j];
#pragma unroll
        for (int f = 0; f < HDIM; ++f) s += g[gi * HDIM + f] * hW1[f * 32 + j];
        s = fmaxf(s, 0.f);
        s = (s - hm[j]) * rsqrtf(hv[j] + 1e-5f) * hgam[j] + hbet[j];
        h1[idx] = s;
    }
    __syncthreads();
    if (t < NGRAPH) {
        float s = hb2[0];
#pragma unroll
        for (int j = 0; j < 32; ++j) s += h1[t * 32 + j] * hW2[j];
        out[t] = s;
    }
}

static inline size_t align_up(size_t x) { return (x + 255) & ~(size_t)255; }

extern "C" void kernel_launch(void* const* d_in, const int* in_sizes, int n_in,
                              void* d_out, int out_size, void* d_ws, size_t ws_size,
                              hipStream_t stream) {
    const float* x    = (const float*)d_in[0];
    const int*   ei   = (const int*)d_in[1];
    const int*   batch= (const int*)d_in[2];
    const float* Wc   = (const float*)d_in[3];
    const float* bc   = (const float*)d_in[4];
    const float* bng  = (const float*)d_in[5];
    const float* bnb  = (const float*)d_in[6];
    const float* bnm  = (const float*)d_in[7];
    const float* bnv  = (const float*)d_in[8];
    const float* hW1  = (const float*)d_in[9];
    const float* hb1  = (const float*)d_in[10];
    const float* hgam = (const float*)d_in[11];
    const float* hbet = (const float*)d_in[12];
    const float* hm   = (const float*)d_in[13];
    const float* hv   = (const float*)d_in[14];
    const float* hW2  = (const float*)d_in[15];
    const float* hb2  = (const float*)d_in[16];
    float* out = (float*)d_out;

    const int N = in_sizes[0] / HDIM;   // 100000
    const int E = in_sizes[1] / 2;      // 1000000

    // ---- workspace carve (all 256B aligned) ----
    char* ws = (char*)d_ws;
    size_t off = 0;
    float* P = (float*)(ws + off);        off += align_up((size_t)N * HDIM * 4);
    float* T = (float*)(ws + off);        off += align_up((size_t)N * HDIM * 4);
    // contiguous zero region: counts | gsum | gcnt
    int*   counts = (int*)(ws + off);
    float* gsum = (float*)(ws + off + (size_t)N * 4);
    float* gcnt = (float*)(ws + off + (size_t)N * 4 + NGRAPH * HDIM * 4);
    int zero_n = N + NGRAPH * HDIM + NGRAPH;
    off += align_up((size_t)zero_n * 4);
    int*   row_ptr = (int*)(ws + off);    off += align_up((size_t)(N + 1) * 4);
    int*   cursor  = (int*)(ws + off);    off += align_up((size_t)N * 4);
    float* dinv    = (float*)(ws + off);  off += align_up((size_t)N * 4);
    int*   bsums   = (int*)(ws + off);    off += align_up(256 * 4);
    int*   csr_src = (int*)(ws + off);    off += align_up((size_t)E * 4);
    float* csr_norm= (float*)(ws + off);  off += align_up((size_t)E * 4);

    int gE = (E + 255) / 256;
    int gN = (N + 255) / 256;
    int nScanBlocks = (N + SCAN_CHUNK - 1) / SCAN_CHUNK;   // 98

    // ---- build degree + CSR ----
    zero_kernel<<<(zero_n + 255) / 256, 256, 0, stream>>>(counts, zero_n);
    count_kernel<<<gE, 256, 0, stream>>>(ei, counts, E);
    bsum_kernel<<<nScanBlocks, 256, 0, stream>>>(counts, bsums, N);
    bscan_kernel<<<1, 256, 0, stream>>>(bsums, nScanBlocks, row_ptr, N, E);
    scan_apply_kernel<<<nScanBlocks, 256, 0, stream>>>(counts, bsums, row_ptr, cursor, dinv, N);
    fill_kernel<<<gE, 256, 0, stream>>>(ei, dinv, cursor, csr_src, csr_norm, E);

    // ---- 5 GCN layers ----
    int aggBlocks = (N + 3) / 4;   // 4 waves (nodes) per 256-thread block
    for (int l = 0; l < 5; ++l) {
        const float* in = (l == 0) ? x : P;
        gemm64_kernel<<<gN, 256, 0, stream>>>(in, Wc + (size_t)l * HDIM * HDIM, T, N);
        aggregate_kernel<<<aggBlocks, 256, 0, stream>>>(
            T, dinv, row_ptr, csr_src, csr_norm,
            bc + l * HDIM, bng + l * HDIM, bnb + l * HDIM, bnm + l * HDIM, bnv + l * HDIM,
            P, N, (l > 0) ? 1 : 0);
    }

    // ---- pool + head ----
    int poolBlocks = (N + 255) / 256;  // each block covers 4 waves x 64 nodes
    pool_kernel<<<poolBlocks, 256, 0, stream>>>(P, batch, gsum, gcnt, N);
    head_kernel<<<1, 256, 0, stream>>>(gsum, gcnt, hW1, hb1, hgam, hbet, hm, hv, hW2, hb2, out);
}

// Round 3
// 677.033 us; speedup vs baseline: 1.5691x; 1.3407x over previous
//
#include <hip/hip_runtime.h>
#include <hip/hip_bf16.h>

// GCN: 5 x (GEMM 64x64 -> CSR gather + bias/ReLU/BN/residual) -> mean-pool -> MLP head.
// R2: hierarchical scan. R3: aggregate edge-loop unrolled x4 (4 gathers in flight),
// csr packed as int2 (src, norm-bits) -> one scalar 8B load per edge.

#define NNODES 100000
#define NEDGES 1000000
#define NGRAPH 64
#define HDIM 64
#define SCAN_CHUNK 1024   // elements per block in the hierarchical scan

// ---------------- zero ----------------
__global__ void zero_kernel(int* __restrict__ p, int n) {
    int i = blockIdx.x * 256 + threadIdx.x;
    if (i < n) p[i] = 0;
}

// ---------------- degree count (in-degree via dst) ----------------
__global__ void count_kernel(const int* __restrict__ ei, int* __restrict__ counts, int E) {
    int e = blockIdx.x * 256 + threadIdx.x;
    if (e < E) atomicAdd(&counts[ei[E + e]], 1);
}

// ---------------- scan level 1: per-block partial sums (1024 elems / block) -----------
__global__ __launch_bounds__(256) void bsum_kernel(const int* __restrict__ counts,
                                                   int* __restrict__ bsums, int N) {
    __shared__ int ws[4];
    int base = blockIdx.x * SCAN_CHUNK + threadIdx.x * 4;
    int s = 0;
    if (base + 3 < N) {
        int4 c = *(const int4*)(counts + base);
        s = c.x + c.y + c.z + c.w;
    } else {
        for (int k = 0; k < 4 && base + k < N; ++k) s += counts[base + k];
    }
    for (int off = 32; off > 0; off >>= 1) s += __shfl_down(s, off, 64);
    int wid = threadIdx.x >> 6;
    if ((threadIdx.x & 63) == 0) ws[wid] = s;
    __syncthreads();
    if (threadIdx.x == 0) bsums[blockIdx.x] = ws[0] + ws[1] + ws[2] + ws[3];
}

// ---------------- scan level 2: single small block scans the partial sums --------------
__global__ __launch_bounds__(256) void bscan_kernel(int* __restrict__ bsums, int nb,
                                                    int* __restrict__ row_ptr, int N, int E) {
    __shared__ int sh[256];
    int t = threadIdx.x;
    sh[t] = (t < nb) ? bsums[t] : 0;
    __syncthreads();
    for (int off = 1; off < 256; off <<= 1) {
        int v = (t >= off) ? sh[t - off] : 0;
        __syncthreads();
        sh[t] += v;
        __syncthreads();
    }
    if (t < nb) bsums[t] = (t == 0) ? 0 : sh[t - 1];  // exclusive block offsets
    if (t == 0) row_ptr[N] = E;                        // total in-degree == E
}

// ---------------- scan level 3: apply — row_ptr + dinv + cursor fused ------------------
__global__ __launch_bounds__(256) void scan_apply_kernel(
    const int* __restrict__ counts, const int* __restrict__ bsums,
    int* __restrict__ row_ptr, int* __restrict__ cursor,
    float* __restrict__ dinv, int N) {
    __shared__ int wsum[4];
    int t = threadIdx.x;
    int lane = t & 63, wid = t >> 6;
    int base = blockIdx.x * SCAN_CHUNK + t * 4;
    int c0 = 0, c1 = 0, c2 = 0, c3 = 0;
    if (base + 3 < N) {
        int4 c = *(const int4*)(counts + base);
        c0 = c.x; c1 = c.y; c2 = c.z; c3 = c.w;
    } else if (base < N) {
        c0 = counts[base];
        if (base + 1 < N) c1 = counts[base + 1];
        if (base + 2 < N) c2 = counts[base + 2];
    }
    int tsum = c0 + c1 + c2 + c3;
    int incl = tsum;
    for (int off = 1; off < 64; off <<= 1) {
        int v = __shfl_up(incl, off, 64);
        if (lane >= off) incl += v;
    }
    if (lane == 63) wsum[wid] = incl;
    __syncthreads();
    int woff = 0;
    for (int w = 0; w < wid; ++w) woff += wsum[w];
    int off0 = bsums[blockIdx.x] + woff + (incl - tsum);
    if (base + 3 < N) {
        int4 rp; rp.x = off0; rp.y = off0 + c0; rp.z = off0 + c0 + c1; rp.w = off0 + c0 + c1 + c2;
        *(int4*)(row_ptr + base) = rp;
        *(int4*)(cursor + base) = rp;
        float4 dv;
        dv.x = rsqrtf((float)(c0 + 1)); dv.y = rsqrtf((float)(c1 + 1));
        dv.z = rsqrtf((float)(c2 + 1)); dv.w = rsqrtf((float)(c3 + 1));
        *(float4*)(dinv + base) = dv;
    } else if (base < N) {
        int run = off0;
        int cs[4] = {c0, c1, c2, c3};
        for (int k = 0; k < 4 && base + k < N; ++k) {
            row_ptr[base + k] = run;
            cursor[base + k] = run;
            dinv[base + k] = rsqrtf((float)(cs[k] + 1));
            run += cs[k];
        }
    }
}

// ---------------- fill CSR buckets: packed (src, norm) int2 ----------------
__global__ void fill_kernel(const int* __restrict__ ei, const float* __restrict__ dinv,
                            int* __restrict__ cursor, int2* __restrict__ csr, int E) {
    int e = blockIdx.x * 256 + threadIdx.x;
    if (e < E) {
        int s = ei[e];
        int d = ei[E + e];
        int p = atomicAdd(&cursor[d], 1);
        csr[p] = make_int2(s, __float_as_int(dinv[s] * dinv[d]));
    }
}

// ---------------- GEMM: T = A(Nx64) @ W(64x64) ----------------
__global__ __launch_bounds__(256) void gemm64_kernel(const float* __restrict__ A,
                                                     const float* __restrict__ W,
                                                     float* __restrict__ T, int N) {
    int row = blockIdx.x * 256 + threadIdx.x;
    if (row >= N) return;
    const float4* arow = (const float4*)(A + (size_t)row * HDIM);
    float acc[HDIM];
#pragma unroll
    for (int j = 0; j < HDIM; ++j) acc[j] = 0.f;
    for (int kk = 0; kk < 16; ++kk) {
        float4 a4 = arow[kk];
        const float* wr = W + kk * 4 * HDIM;
#pragma unroll
        for (int j = 0; j < HDIM; ++j) acc[j] += a4.x * wr[j];
#pragma unroll
        for (int j = 0; j < HDIM; ++j) acc[j] += a4.y * wr[HDIM + j];
#pragma unroll
        for (int j = 0; j < HDIM; ++j) acc[j] += a4.z * wr[2 * HDIM + j];
#pragma unroll
        for (int j = 0; j < HDIM; ++j) acc[j] += a4.w * wr[3 * HDIM + j];
    }
    float4* orow = (float4*)(T + (size_t)row * HDIM);
#pragma unroll
    for (int j = 0; j < 16; ++j)
        orow[j] = make_float4(acc[4 * j], acc[4 * j + 1], acc[4 * j + 2], acc[4 * j + 3]);
}

// ------- gather + bias + ReLU + BN + residual (one wave/node, 4 gathers in flight) -----
__global__ __launch_bounds__(256) void aggregate_kernel(
    const float* __restrict__ T, const float* __restrict__ dinv,
    const int* __restrict__ row_ptr, const int2* __restrict__ csr,
    const float* __restrict__ bias, const float* __restrict__ gamma,
    const float* __restrict__ beta, const float* __restrict__ mean,
    const float* __restrict__ var,
    float* __restrict__ P, int N, int residual) {
    int node = (blockIdx.x * 256 + threadIdx.x) >> 6;
    int lane = threadIdx.x & 63;
    if (node >= N) return;
    float di = dinv[node];
    float acc = T[(size_t)node * HDIM + lane] * di * di;  // self-loop
    int e0 = row_ptr[node], e1 = row_ptr[node + 1];
    float a0 = 0.f, a1 = 0.f, a2 = 0.f, a3 = 0.f;
    int e = e0;
    for (; e + 4 <= e1; e += 4) {
        // wave-uniform -> scalar loads; 4 independent vector gathers in flight
        int2 c0 = csr[e], c1 = csr[e + 1], c2 = csr[e + 2], c3 = csr[e + 3];
        float t0 = T[(size_t)c0.x * HDIM + lane];
        float t1 = T[(size_t)c1.x * HDIM + lane];
        float t2 = T[(size_t)c2.x * HDIM + lane];
        float t3 = T[(size_t)c3.x * HDIM + lane];
        a0 += t0 * __int_as_float(c0.y);
        a1 += t1 * __int_as_float(c1.y);
        a2 += t2 * __int_as_float(c2.y);
        a3 += t3 * __int_as_float(c3.y);
    }
    for (; e < e1; ++e) {
        int2 c = csr[e];
        acc += T[(size_t)c.x * HDIM + lane] * __int_as_float(c.y);
    }
    acc += (a0 + a1) + (a2 + a3);
    float v = acc + bias[lane];
    v = fmaxf(v, 0.f);
    v = (v - mean[lane]) * rsqrtf(var[lane] + 1e-5f) * gamma[lane] + beta[lane];
    if (residual) v += P[(size_t)node * HDIM + lane];
    P[(size_t)node * HDIM + lane] = v;
}

// ---------------- mean-pool: per-wave run accumulation over sorted batch ---------------
__global__ __launch_bounds__(256) void pool_kernel(const float* __restrict__ P,
                                                   const int* __restrict__ batch,
                                                   float* __restrict__ gsum,
                                                   float* __restrict__ gcnt, int N) {
    int wave = (blockIdx.x * 256 + threadIdx.x) >> 6;
    int lane = threadIdx.x & 63;
    int start = wave * 64;
    if (start >= N) return;
    int end = start + 64; if (end > N) end = N;
    float acc = 0.f;
    int cur = batch[start];
    int cnt = 0;
    for (int i = start; i < end; ++i) {
        int b = batch[i];
        if (b != cur) {
            atomicAdd(&gsum[cur * HDIM + lane], acc);
            if (lane == 0) atomicAdd(&gcnt[cur], (float)cnt);
            cur = b; acc = 0.f; cnt = 0;
        }
        acc += P[(size_t)i * HDIM + lane];
        cnt++;
    }
    atomicAdd(&gsum[cur * HDIM + lane], acc);
    if (lane == 0) atomicAdd(&gcnt[cur], (float)cnt);
}

// ---------------- MLP head (single block) ----------------
__global__ __launch_bounds__(256) void head_kernel(
    const float* __restrict__ gsum, const float* __restrict__ gcnt,
    const float* __restrict__ hW1, const float* __restrict__ hb1,
    const float* __restrict__ hgam, const float* __restrict__ hbet,
    const float* __restrict__ hm, const float* __restrict__ hv,
    const float* __restrict__ hW2, const float* __restrict__ hb2,
    float* __restrict__ out) {
    __shared__ float g[NGRAPH * HDIM];
    __shared__ float h1[NGRAPH * 32];
    int t = threadIdx.x;
    for (int idx = t; idx < NGRAPH * HDIM; idx += 256) {
        int gi = idx >> 6;
        g[idx] = gsum[idx] / fmaxf(gcnt[gi], 1.f);
    }
    __syncthreads();
    for (int idx = t; idx < NGRAPH * 32; idx += 256) {
        int gi = idx >> 5, j = idx & 31;
        float s = hb1[j];
#pragma unroll
        for (int f = 0; f < HDIM; ++f) s += g[gi * HDIM + f] * hW1[f * 32 + j];
        s = fmaxf(s, 0.f);
        s = (s - hm[j]) * rsqrtf(hv[j] + 1e-5f) * hgam[j] + hbet[j];
        h1[idx] = s;
    }
    __syncthreads();
    if (t < NGRAPH) {
        float s = hb2[0];
#pragma unroll
        for (int j = 0; j < 32; ++j) s += h1[t * 32 + j] * hW2[j];
        out[t] = s;
    }
}

static inline size_t align_up(size_t x) { return (x + 255) & ~(size_t)255; }

extern "C" void kernel_launch(void* const* d_in, const int* in_sizes, int n_in,
                              void* d_out, int out_size, void* d_ws, size_t ws_size,
                              hipStream_t stream) {
    const float* x    = (const float*)d_in[0];
    const int*   ei   = (const int*)d_in[1];
    const int*   batch= (const int*)d_in[2];
    const float* Wc   = (const float*)d_in[3];
    const float* bc   = (const float*)d_in[4];
    const float* bng  = (const float*)d_in[5];
    const float* bnb  = (const float*)d_in[6];
    const float* bnm  = (const float*)d_in[7];
    const float* bnv  = (const float*)d_in[8];
    const float* hW1  = (const float*)d_in[9];
    const float* hb1  = (const float*)d_in[10];
    const float* hgam = (const float*)d_in[11];
    const float* hbet = (const float*)d_in[12];
    const float* hm   = (const float*)d_in[13];
    const float* hv   = (const float*)d_in[14];
    const float* hW2  = (const float*)d_in[15];
    const float* hb2  = (const float*)d_in[16];
    float* out = (float*)d_out;

    const int N = in_sizes[0] / HDIM;   // 100000
    const int E = in_sizes[1] / 2;      // 1000000

    // ---- workspace carve (all 256B aligned) ----
    char* ws = (char*)d_ws;
    size_t off = 0;
    float* P = (float*)(ws + off);        off += align_up((size_t)N * HDIM * 4);
    float* T = (float*)(ws + off);        off += align_up((size_t)N * HDIM * 4);
    int*   counts = (int*)(ws + off);
    float* gsum = (float*)(ws + off + (size_t)N * 4);
    float* gcnt = (float*)(ws + off + (size_t)N * 4 + NGRAPH * HDIM * 4);
    int zero_n = N + NGRAPH * HDIM + NGRAPH;
    off += align_up((size_t)zero_n * 4);
    int*   row_ptr = (int*)(ws + off);    off += align_up((size_t)(N + 1) * 4);
    int*   cursor  = (int*)(ws + off);    off += align_up((size_t)N * 4);
    float* dinv    = (float*)(ws + off);  off += align_up((size_t)N * 4);
    int*   bsums   = (int*)(ws + off);    off += align_up(256 * 4);
    int2*  csr     = (int2*)(ws + off);   off += align_up((size_t)E * 8);

    int gE = (E + 255) / 256;
    int gN = (N + 255) / 256;
    int nScanBlocks = (N + SCAN_CHUNK - 1) / SCAN_CHUNK;   // 98

    // ---- build degree + CSR ----
    zero_kernel<<<(zero_n + 255) / 256, 256, 0, stream>>>(counts, zero_n);
    count_kernel<<<gE, 256, 0, stream>>>(ei, counts, E);
    bsum_kernel<<<nScanBlocks, 256, 0, stream>>>(counts, bsums, N);
    bscan_kernel<<<1, 256, 0, stream>>>(bsums, nScanBlocks, row_ptr, N, E);
    scan_apply_kernel<<<nScanBlocks, 256, 0, stream>>>(counts, bsums, row_ptr, cursor, dinv, N);
    fill_kernel<<<gE, 256, 0, stream>>>(ei, dinv, cursor, csr, E);

    // ---- 5 GCN layers ----
    int aggBlocks = (N + 3) / 4;   // 4 waves (nodes) per 256-thread block
    for (int l = 0; l < 5; ++l) {
        const float* in = (l == 0) ? x : P;
        gemm64_kernel<<<gN, 256, 0, stream>>>(in, Wc + (size_t)l * HDIM * HDIM, T, N);
        aggregate_kernel<<<aggBlocks, 256, 0, stream>>>(
            T, dinv, row_ptr, csr,
            bc + l * HDIM, bng + l * HDIM, bnb + l * HDIM, bnm + l * HDIM, bnv + l * HDIM,
            P, N, (l > 0) ? 1 : 0);
    }

    // ---- pool + head ----
    int poolBlocks = (N + 255) / 256;
    pool_kernel<<<poolBlocks, 256, 0, stream>>>(P, batch, gsum, gcnt, N);
    head_kernel<<<1, 256, 0, stream>>>(gsum, gcnt, hW1, hb1, hgam, hbet, hm, hv, hW2, hb2, out);
}